// Round 1
// baseline (10214.706 us; speedup 1.0000x reference)
//
#include <hip/hip_runtime.h>
#include <hip/hip_bf16.h>
#include <math.h>

#define N_NODES 100000
#define N_EDGES 1600000
#define ET (N_EDGES + N_NODES)   // edges + self-loops
#define N_GRAPHS 512
#define NEG_SLOPE 0.2f

// ---- atomic helpers ------------------------------------------------------
// float atomic max via two-sided int trick; dst must be initialized to -inf
__device__ __forceinline__ void atomMaxF(float* addr, float val) {
    if (val >= 0.f) atomicMax((int*)addr, __float_as_int(val));
    else            atomicMin((unsigned int*)addr, __float_as_uint(val));
}
// HW f32 atomic add (coarse-grained memory -> safe), avoids CAS loop
__device__ __forceinline__ void atomAddF(float* p, float v) {
    unsafeAtomicAdd(p, v);
}

__device__ __forceinline__ float lrelu(float v) {
    return v >= 0.f ? v : NEG_SLOPE * v;
}

// ---- init ----------------------------------------------------------------
__global__ void k_fill_neginf(float* __restrict__ p, int n) {
    int i = blockIdx.x * blockDim.x + threadIdx.x;
    if (i < n) p[i] = -INFINITY;
}

__global__ void k_out_init(float* __restrict__ out, const float* __restrict__ bg) {
    int i = blockIdx.x * blockDim.x + threadIdx.x;
    if (i < N_GRAPHS) out[i] = bg[0];
}

// ---- conv1 features: h1 = x@W1 [N,64]; a1s/a1d = per-head att dots [N,8] --
__global__ __launch_bounds__(256) void k_feat1(
    const float* __restrict__ x, const float* __restrict__ W1,
    const float* __restrict__ as1, const float* __restrict__ ad1,
    float* __restrict__ h1, float* __restrict__ a1s, float* __restrict__ a1d)
{
    __shared__ float xs[4][76];
    const int g = threadIdx.x >> 6;    // node sub-group (one wave each)
    const int c = threadIdx.x & 63;    // output channel
    const int n = blockIdx.x * 4 + g;  // grid = N/4 exactly (N%4==0)
    const float* xr = x + (long)n * 75;
    xs[g][c] = xr[c];
    if (c < 11) xs[g][64 + c] = xr[64 + c];
    __syncthreads();
    float h = 0.f;
    #pragma unroll
    for (int k = 0; k < 75; ++k) h += xs[g][k] * W1[k * 64 + c];
    h1[(long)n * 64 + c] = h;
    const int head = c >> 3, lane = c & 7;
    float vs = h * as1[c];   // att_src1[head][c&7] == as1[c]
    float vd = h * ad1[c];
    #pragma unroll
    for (int off = 1; off < 8; off <<= 1) {
        vs += __shfl_xor(vs, off, 64);
        vd += __shfl_xor(vd, off, 64);
    }
    if (lane == 0) { a1s[n * 8 + head] = vs; a1d[n * 8 + head] = vd; }
}

// ---- conv1 edge pass A: segment max of leakyrelu(e) per (dst, head) ------
__global__ __launch_bounds__(256) void k_edge1_max(
    const int* __restrict__ ei, const float* __restrict__ a1s,
    const float* __restrict__ a1d, float* __restrict__ m1)
{
    int e = blockIdx.x * 256 + threadIdx.x;
    if (e >= ET) return;
    int src, dst;
    if (e < N_EDGES) { src = ei[e]; dst = ei[N_EDGES + e]; }
    else             { src = dst = e - N_EDGES; }
    const float4* ps = (const float4*)(a1s + (long)src * 8);
    const float4* pd = (const float4*)(a1d + (long)dst * 8);
    float4 s0 = ps[0], s1 = ps[1], d0 = pd[0], d1 = pd[1];
    float ev[8] = { s0.x + d0.x, s0.y + d0.y, s0.z + d0.z, s0.w + d0.w,
                    s1.x + d1.x, s1.y + d1.y, s1.z + d1.z, s1.w + d1.w };
    #pragma unroll
    for (int hh = 0; hh < 8; ++hh) atomMaxF(m1 + (long)dst * 8 + hh, lrelu(ev[hh]));
}

// ---- conv1 edge pass B: denom += ee; acc += ee*h1[src]  (8 threads/edge) -
__global__ __launch_bounds__(256) void k_edge1_sum(
    const int* __restrict__ ei, const float* __restrict__ a1s,
    const float* __restrict__ a1d, const float* __restrict__ m1,
    const float* __restrict__ h1, float* __restrict__ den1, float* __restrict__ acc1)
{
    long gid = (long)blockIdx.x * 256 + threadIdx.x;
    int e  = (int)(gid >> 3);
    int hh = (int)(gid & 7);       // head handled by this thread
    if (e >= ET) return;
    int src, dst;
    if (e < N_EDGES) { src = ei[e]; dst = ei[N_EDGES + e]; }
    else             { src = dst = e - N_EDGES; }
    float v  = lrelu(a1s[(long)src * 8 + hh] + a1d[(long)dst * 8 + hh]);
    float ee = __expf(v - m1[(long)dst * 8 + hh]);
    atomAddF(den1 + (long)dst * 8 + hh, ee);
    const float4* hs = (const float4*)(h1 + (long)src * 64 + hh * 8);
    float4 h0 = hs[0], h4 = hs[1];
    float* ac = acc1 + (long)dst * 64 + hh * 8;
    atomAddF(ac + 0, ee * h0.x); atomAddF(ac + 1, ee * h0.y);
    atomAddF(ac + 2, ee * h0.z); atomAddF(ac + 3, ee * h0.w);
    atomAddF(ac + 4, ee * h4.x); atomAddF(ac + 5, ee * h4.y);
    atomAddF(ac + 6, ee * h4.z); atomAddF(ac + 7, ee * h4.w);
}

// ---- conv1 epilogue: x2 = elu(acc/denom + bias) --------------------------
__global__ void k_x2(const float* __restrict__ acc1, const float* __restrict__ den1,
                     const float* __restrict__ bias1, float* __restrict__ x2)
{
    int i = blockIdx.x * 256 + threadIdx.x;
    if (i >= N_NODES * 64) return;
    int n = i >> 6, c = i & 63;
    float v = acc1[i] / den1[n * 8 + (c >> 3)] + bias1[c];
    x2[i] = v > 0.f ? v : (__expf(v) - 1.f);
}

// ---- conv2 features: h2 = x2@W2 [N,128]; a2s/a2d [N] ---------------------
__global__ __launch_bounds__(128) void k_feat2(
    const float* __restrict__ x2, const float* __restrict__ W2,
    const float* __restrict__ as2, const float* __restrict__ ad2,
    float* __restrict__ h2, float* __restrict__ a2s, float* __restrict__ a2d)
{
    __shared__ float xs[64];
    __shared__ float red[4];
    const int n = blockIdx.x;
    const int c = threadIdx.x;
    if (c < 64) xs[c] = x2[(long)n * 64 + c];
    __syncthreads();
    float h = 0.f;
    #pragma unroll
    for (int k = 0; k < 64; ++k) h += xs[k] * W2[k * 128 + c];
    h2[(long)n * 128 + c] = h;
    float vs = h * as2[c], vd = h * ad2[c];
    #pragma unroll
    for (int off = 1; off < 64; off <<= 1) {
        vs += __shfl_xor(vs, off, 64);
        vd += __shfl_xor(vd, off, 64);
    }
    const int w = c >> 6;
    if ((c & 63) == 0) { red[w * 2] = vs; red[w * 2 + 1] = vd; }
    __syncthreads();
    if (c == 0) { a2s[n] = red[0] + red[2]; a2d[n] = red[1] + red[3]; }
}

// ---- conv2 edge pass A ---------------------------------------------------
__global__ __launch_bounds__(256) void k_edge2_max(
    const int* __restrict__ ei, const float* __restrict__ a2s,
    const float* __restrict__ a2d, float* __restrict__ m2)
{
    int e = blockIdx.x * 256 + threadIdx.x;
    if (e >= ET) return;
    int src, dst;
    if (e < N_EDGES) { src = ei[e]; dst = ei[N_EDGES + e]; }
    else             { src = dst = e - N_EDGES; }
    atomMaxF(m2 + dst, lrelu(a2s[src] + a2d[dst]));
}

// ---- conv2 edge pass B: 16 threads/edge, 8 channels each -----------------
__global__ __launch_bounds__(256) void k_edge2_sum(
    const int* __restrict__ ei, const float* __restrict__ a2s,
    const float* __restrict__ a2d, const float* __restrict__ m2,
    const float* __restrict__ h2, float* __restrict__ den2, float* __restrict__ acc2)
{
    long gid = (long)blockIdx.x * 256 + threadIdx.x;
    int e = (int)(gid >> 4);
    int l = (int)(gid & 15);
    if (e >= ET) return;
    int src, dst;
    if (e < N_EDGES) { src = ei[e]; dst = ei[N_EDGES + e]; }
    else             { src = dst = e - N_EDGES; }
    float v  = lrelu(a2s[src] + a2d[dst]);
    float ee = __expf(v - m2[dst]);
    if (l == 0) atomAddF(den2 + dst, ee);
    const float4* hs = (const float4*)(h2 + (long)src * 128 + l * 8);
    float4 h0 = hs[0], h4 = hs[1];
    float* ac = acc2 + (long)dst * 128 + l * 8;
    atomAddF(ac + 0, ee * h0.x); atomAddF(ac + 1, ee * h0.y);
    atomAddF(ac + 2, ee * h0.z); atomAddF(ac + 3, ee * h0.w);
    atomAddF(ac + 4, ee * h4.x); atomAddF(ac + 5, ee * h4.y);
    atomAddF(ac + 6, ee * h4.z); atomAddF(ac + 7, ee * h4.w);
}

// ---- final: x4 = acc2/den2 + bias2; out[batch[n]] += x4 . Wg -------------
__global__ __launch_bounds__(256) void k_final(
    const float* __restrict__ acc2, const float* __restrict__ den2,
    const float* __restrict__ bias2, const float* __restrict__ Wg,
    const int* __restrict__ batch, float* __restrict__ out)
{
    const int n = blockIdx.x * 4 + (threadIdx.x >> 6);  // grid = N/4 exactly
    const int t = threadIdx.x & 63;
    const float inv = 1.f / den2[n];
    float s = 0.f;
    #pragma unroll
    for (int j = 0; j < 2; ++j) {
        int c = t + j * 64;
        float v = acc2[(long)n * 128 + c] * inv + bias2[c];
        s += v * Wg[c];
    }
    #pragma unroll
    for (int off = 1; off < 64; off <<= 1) s += __shfl_xor(s, off, 64);
    if (t == 0) atomAddF(out + batch[n], s);
}

extern "C" void kernel_launch(void* const* d_in, const int* in_sizes, int n_in,
                              void* d_out, int out_size, void* d_ws, size_t ws_size,
                              hipStream_t stream) {
    (void)in_sizes; (void)n_in; (void)out_size; (void)ws_size;
    const float* x     = (const float*)d_in[0];
    const int*   ei    = (const int*)d_in[1];
    const int*   batch = (const int*)d_in[2];
    const float* W1    = (const float*)d_in[3];
    const float* as1   = (const float*)d_in[4];
    const float* ad1   = (const float*)d_in[5];
    const float* b1    = (const float*)d_in[6];
    const float* W2    = (const float*)d_in[7];
    const float* as2   = (const float*)d_in[8];
    const float* ad2   = (const float*)d_in[9];
    const float* b2    = (const float*)d_in[10];
    const float* Wg    = (const float*)d_in[11];
    const float* bg    = (const float*)d_in[12];
    float* out = (float*)d_out;

    // Workspace layout (floats). Total N*356*4 B = 142.4 MB.
    float* ws  = (float*)d_ws;
    const long N = N_NODES;
    float* h1   = ws;             // [N,64]
    float* a1s  = ws + N * 64;    // [N,8]
    float* a1d  = ws + N * 72;    // [N,8]
    float* m1   = ws + N * 80;    // [N,8]
    float* den1 = ws + N * 88;    // [N,8]
    float* acc1 = ws + N * 96;    // [N,64]
    float* x2   = ws + N * 160;   // [N,64]
    float* h2   = ws + N * 224;   // [N,128]
    float* a2s  = ws + N * 352;   // [N]
    float* a2d  = ws + N * 353;   // [N]
    float* m2   = ws + N * 354;   // [N]
    float* den2 = ws + N * 355;   // [N]
    float* acc2 = ws;             // [N,128] aliases h1..acc1 (dead after k_feat2)

    // ---- conv1 ----
    hipMemsetAsync(den1, 0, N * 8 * sizeof(float), stream);
    hipMemsetAsync(acc1, 0, N * 64 * sizeof(float), stream);
    k_fill_neginf<<<(N * 8 + 255) / 256, 256, 0, stream>>>(m1, N * 8);
    k_feat1<<<N / 4, 256, 0, stream>>>(x, W1, as1, ad1, h1, a1s, a1d);
    k_edge1_max<<<(ET + 255) / 256, 256, 0, stream>>>(ei, a1s, a1d, m1);
    k_edge1_sum<<<((long)ET * 8 + 255) / 256, 256, 0, stream>>>(ei, a1s, a1d, m1, h1, den1, acc1);
    k_x2<<<(N * 64 + 255) / 256, 256, 0, stream>>>(acc1, den1, b1, x2);

    // ---- conv2 ----
    k_feat2<<<N, 128, 0, stream>>>(x2, W2, as2, ad2, h2, a2s, a2d);
    hipMemsetAsync(den2, 0, N * sizeof(float), stream);
    hipMemsetAsync(acc2, 0, N * 128 * sizeof(float), stream);
    k_fill_neginf<<<(N + 255) / 256, 256, 0, stream>>>(m2, N);
    k_edge2_max<<<(ET + 255) / 256, 256, 0, stream>>>(ei, a2s, a2d, m2);
    k_edge2_sum<<<((long)ET * 16 + 255) / 256, 256, 0, stream>>>(ei, a2s, a2d, m2, h2, den2, acc2);

    // ---- pool + linear ----
    k_out_init<<<2, 256, 0, stream>>>(out, bg);
    k_final<<<N / 4, 256, 0, stream>>>(acc2, den2, b2, Wg, batch, out);
}

// Round 2
// 1004.317 us; speedup vs baseline: 10.1708x; 10.1708x over previous
//
#include <hip/hip_runtime.h>
#include <hip/hip_bf16.h>
#include <math.h>

#define N_NODES 100000
#define N_EDGES 1600000
#define ET (N_EDGES + N_NODES)   // edges + self-loops
#define N_GRAPHS 512
#define NEG_SLOPE 0.2f
#define SCAN_BS 1024
#define NB_SCAN ((N_NODES + SCAN_BS - 1) / SCAN_BS)   // 98

__device__ __forceinline__ void atomAddF(float* p, float v) { unsafeAtomicAdd(p, v); }
__device__ __forceinline__ float lrelu(float v) { return v >= 0.f ? v : NEG_SLOPE * v; }

// ---- init ----------------------------------------------------------------
__global__ void k_out_init(float* __restrict__ out, const float* __restrict__ bg) {
    int i = blockIdx.x * blockDim.x + threadIdx.x;
    if (i < N_GRAPHS) out[i] = bg[0];
}

// ---- CSR build -----------------------------------------------------------
__global__ __launch_bounds__(256) void k_deg(const int* __restrict__ ei, int* __restrict__ deg) {
    int e = blockIdx.x * 256 + threadIdx.x;
    if (e >= ET) return;
    int dst = (e < N_EDGES) ? ei[N_EDGES + e] : (e - N_EDGES);
    atomicAdd(deg + dst, 1);
}

// block-local exclusive scan; excl[i] = local exclusive, bsum[b] = block total
__global__ __launch_bounds__(SCAN_BS) void k_scan1(const int* __restrict__ deg,
                                                   int* __restrict__ excl, int* __restrict__ bsum) {
    __shared__ int sh[SCAN_BS];
    const int t = threadIdx.x;
    const int i = blockIdx.x * SCAN_BS + t;
    int v = (i < N_NODES) ? deg[i] : 0;
    sh[t] = v;
    __syncthreads();
    for (int off = 1; off < SCAN_BS; off <<= 1) {
        int a = (t >= off) ? sh[t - off] : 0;
        __syncthreads();
        sh[t] += a;
        __syncthreads();
    }
    if (i < N_NODES) excl[i] = sh[t] - v;
    if (t == SCAN_BS - 1) bsum[blockIdx.x] = sh[t];
}

// single-block exclusive scan of the NB_SCAN block sums (in place)
__global__ __launch_bounds__(128) void k_scan2(int* __restrict__ bsum) {
    __shared__ int sh[128];
    const int t = threadIdx.x;
    int v = (t < NB_SCAN) ? bsum[t] : 0;
    sh[t] = v;
    __syncthreads();
    for (int off = 1; off < 128; off <<= 1) {
        int a = (t >= off) ? sh[t - off] : 0;
        __syncthreads();
        sh[t] += a;
        __syncthreads();
    }
    if (t < NB_SCAN) bsum[t] = sh[t] - v;   // exclusive
}

// rowptr = excl + blockOffset; cursor = copy; rowptr[N] = ET
__global__ __launch_bounds__(256) void k_scan3(const int* __restrict__ excl, const int* __restrict__ bsum,
                                               int* __restrict__ rowptr, int* __restrict__ cursor) {
    int i = blockIdx.x * 256 + threadIdx.x;
    if (i < N_NODES) {
        int r = excl[i] + bsum[i / SCAN_BS];
        rowptr[i] = r;
        cursor[i] = r;
    }
    if (i == 0) rowptr[N_NODES] = ET;
}

__global__ __launch_bounds__(256) void k_fill(const int* __restrict__ ei,
                                              int* __restrict__ cursor, int* __restrict__ ecol) {
    int e = blockIdx.x * 256 + threadIdx.x;
    if (e >= ET) return;
    int src, dst;
    if (e < N_EDGES) { src = ei[e]; dst = ei[N_EDGES + e]; }
    else             { src = dst = e - N_EDGES; }
    int slot = atomicAdd(cursor + dst, 1);
    ecol[slot] = src;
}

// ---- conv1 features: h1 = x@W1 [N,64]; a1s/a1d = per-head att dots [N,8] --
__global__ __launch_bounds__(256) void k_feat1(
    const float* __restrict__ x, const float* __restrict__ W1,
    const float* __restrict__ as1, const float* __restrict__ ad1,
    float* __restrict__ h1, float* __restrict__ a1s, float* __restrict__ a1d)
{
    __shared__ float xs[4][76];
    const int g = threadIdx.x >> 6;    // node sub-group (one wave each)
    const int c = threadIdx.x & 63;    // output channel
    const int n = blockIdx.x * 4 + g;  // grid = N/4 exactly
    const float* xr = x + (long)n * 75;
    xs[g][c] = xr[c];
    if (c < 11) xs[g][64 + c] = xr[64 + c];
    __syncthreads();
    float h = 0.f;
    #pragma unroll
    for (int k = 0; k < 75; ++k) h += xs[g][k] * W1[k * 64 + c];
    h1[(long)n * 64 + c] = h;
    const int head = c >> 3, lane = c & 7;
    float vs = h * as1[c];
    float vd = h * ad1[c];
    #pragma unroll
    for (int off = 1; off < 8; off <<= 1) {
        vs += __shfl_xor(vs, off, 64);
        vd += __shfl_xor(vd, off, 64);
    }
    if (lane == 0) { a1s[n * 8 + head] = vs; a1d[n * 8 + head] = vd; }
}

// ---- conv1 gather: one wave per dst node; fused softmax+aggregate+ELU ----
// lane c in [0,64): channel c, head = c>>3.
__global__ __launch_bounds__(256) void k_gat1(
    const int* __restrict__ rowptr, const int* __restrict__ ecol,
    const float* __restrict__ a1s, const float* __restrict__ a1d,
    const float* __restrict__ h1, const float* __restrict__ bias1,
    float* __restrict__ x2)
{
    const int dst  = blockIdx.x * 4 + (threadIdx.x >> 6);  // grid = N/4
    const int lane = threadIdx.x & 63;
    const int beg = rowptr[dst], end = rowptr[dst + 1];

    // phase 1: per-head max. lane = (group g = lane>>3) x (head hh = lane&7)
    const int hh = lane & 7;
    const float ad_h = a1d[(long)dst * 8 + hh];
    float mx = -INFINITY;
    for (int j = beg + (lane >> 3); j < end; j += 8) {
        int s = ecol[j];
        mx = fmaxf(mx, lrelu(a1s[(long)s * 8 + hh] + ad_h));
    }
    mx = fmaxf(mx, __shfl_xor(mx, 8, 64));
    mx = fmaxf(mx, __shfl_xor(mx, 16, 64));
    mx = fmaxf(mx, __shfl_xor(mx, 32, 64));
    // lane h (h<8) now holds the max for head h

    // phase 2: edges sequential, channels lane-parallel
    const int head = lane >> 3;
    const float m   = __shfl(mx, head, 64);
    const float adc = a1d[(long)dst * 8 + head];
    float acc = 0.f, den = 0.f;
    for (int j = beg; j < end; ++j) {
        int s = ecol[j];
        float e  = lrelu(a1s[(long)s * 8 + head] + adc);
        float ee = __expf(e - m);
        den += ee;
        acc += ee * h1[(long)s * 64 + lane];
    }
    float v = acc / den + bias1[lane];
    x2[(long)dst * 64 + lane] = v > 0.f ? v : (__expf(v) - 1.f);
}

// ---- conv2 features: h2 = x2@W2 [N,128]; a2s/a2d [N] ---------------------
__global__ __launch_bounds__(128) void k_feat2(
    const float* __restrict__ x2, const float* __restrict__ W2,
    const float* __restrict__ as2, const float* __restrict__ ad2,
    float* __restrict__ h2, float* __restrict__ a2s, float* __restrict__ a2d)
{
    __shared__ float xs[64];
    __shared__ float red[4];
    const int n = blockIdx.x;
    const int c = threadIdx.x;
    if (c < 64) xs[c] = x2[(long)n * 64 + c];
    __syncthreads();
    float h = 0.f;
    #pragma unroll
    for (int k = 0; k < 64; ++k) h += xs[k] * W2[k * 128 + c];
    h2[(long)n * 128 + c] = h;
    float vs = h * as2[c], vd = h * ad2[c];
    #pragma unroll
    for (int off = 1; off < 64; off <<= 1) {
        vs += __shfl_xor(vs, off, 64);
        vd += __shfl_xor(vd, off, 64);
    }
    const int w = c >> 6;
    if ((c & 63) == 0) { red[w * 2] = vs; red[w * 2 + 1] = vd; }
    __syncthreads();
    if (c == 0) { a2s[n] = red[0] + red[2]; a2d[n] = red[1] + red[3]; }
}

// ---- conv2 gather + pool + linear, fully fused ---------------------------
// one wave per dst node; lane handles channels {lane, lane+64}
__global__ __launch_bounds__(256) void k_gat2(
    const int* __restrict__ rowptr, const int* __restrict__ ecol,
    const float* __restrict__ a2s, const float* __restrict__ a2d,
    const float* __restrict__ h2, const float* __restrict__ bias2,
    const float* __restrict__ Wg, const int* __restrict__ batch,
    float* __restrict__ out)
{
    const int dst  = blockIdx.x * 4 + (threadIdx.x >> 6);  // grid = N/4
    const int lane = threadIdx.x & 63;
    const int beg = rowptr[dst], end = rowptr[dst + 1];
    const float adv = a2d[dst];

    // phase 1: max over edges (lanes parallel)
    float mx = -INFINITY;
    for (int j = beg + lane; j < end; j += 64)
        mx = fmaxf(mx, lrelu(a2s[ecol[j]] + adv));
    #pragma unroll
    for (int off = 1; off < 64; off <<= 1) mx = fmaxf(mx, __shfl_xor(mx, off, 64));

    // phase 2: edges sequential, channels parallel
    float acc0 = 0.f, acc1 = 0.f, den = 0.f;
    for (int j = beg; j < end; ++j) {
        int s = ecol[j];
        float ee = __expf(lrelu(a2s[s] + adv) - mx);
        den += ee;
        const float* hr = h2 + (long)s * 128;
        acc0 += ee * hr[lane];
        acc1 += ee * hr[lane + 64];
    }
    const float inv = 1.f / den;
    float v0 = acc0 * inv + bias2[lane];
    float v1 = acc1 * inv + bias2[lane + 64];
    float s = v0 * Wg[lane] + v1 * Wg[lane + 64];
    #pragma unroll
    for (int off = 1; off < 64; off <<= 1) s += __shfl_xor(s, off, 64);
    if (lane == 0) atomAddF(out + batch[dst], s);
}

extern "C" void kernel_launch(void* const* d_in, const int* in_sizes, int n_in,
                              void* d_out, int out_size, void* d_ws, size_t ws_size,
                              hipStream_t stream) {
    (void)in_sizes; (void)n_in; (void)out_size; (void)ws_size;
    const float* x     = (const float*)d_in[0];
    const int*   ei    = (const int*)d_in[1];
    const int*   batch = (const int*)d_in[2];
    const float* W1    = (const float*)d_in[3];
    const float* as1   = (const float*)d_in[4];
    const float* ad1   = (const float*)d_in[5];
    const float* b1    = (const float*)d_in[6];
    const float* W2    = (const float*)d_in[7];
    const float* as2   = (const float*)d_in[8];
    const float* ad2   = (const float*)d_in[9];
    const float* b2    = (const float*)d_in[10];
    const float* Wg    = (const float*)d_in[11];
    const float* bg    = (const float*)d_in[12];
    float* out = (float*)d_out;

    // ---- workspace layout ----
    const long N = N_NODES;
    char* p = (char*)d_ws;
    int* deg    = (int*)p;            p += (N)         * sizeof(int);
    int* excl   = (int*)p;            p += (N)         * sizeof(int);
    int* rowptr = (int*)p;            p += (N + 1)     * sizeof(int);
    int* cursor = (int*)p;            p += (N)         * sizeof(int);
    int* bsum   = (int*)p;            p += 128         * sizeof(int);
    int* ecol   = (int*)p;            p += (long)ET    * sizeof(int);
    float* h1   = (float*)p;          p += N * 64      * sizeof(float);
    float* a1s  = (float*)p;          p += N * 8       * sizeof(float);
    float* a1d  = (float*)p;          p += N * 8       * sizeof(float);
    float* x2   = (float*)p;          p += N * 64      * sizeof(float);
    float* h2   = (float*)p;          p += N * 128     * sizeof(float);
    float* a2s  = (float*)p;          p += N           * sizeof(float);
    float* a2d  = (float*)p;          p += N           * sizeof(float);

    // ---- CSR build (per call; inputs are restored before every launch) ----
    hipMemsetAsync(deg, 0, N * sizeof(int), stream);
    k_deg  <<<(ET + 255) / 256, 256, 0, stream>>>(ei, deg);
    k_scan1<<<NB_SCAN, SCAN_BS, 0, stream>>>(deg, excl, bsum);
    k_scan2<<<1, 128, 0, stream>>>(bsum);
    k_scan3<<<(N_NODES + 255) / 256, 256, 0, stream>>>(excl, bsum, rowptr, cursor);
    k_fill <<<(ET + 255) / 256, 256, 0, stream>>>(ei, cursor, ecol);

    // ---- conv1 ----
    k_feat1<<<N_NODES / 4, 256, 0, stream>>>(x, W1, as1, ad1, h1, a1s, a1d);
    k_gat1 <<<N_NODES / 4, 256, 0, stream>>>(rowptr, ecol, a1s, a1d, h1, b1, x2);

    // ---- conv2 + pool + linear ----
    k_feat2<<<N_NODES, 128, 0, stream>>>(x2, W2, as2, ad2, h2, a2s, a2d);
    k_out_init<<<2, 256, 0, stream>>>(out, bg);
    k_gat2 <<<N_NODES / 4, 256, 0, stream>>>(rowptr, ecol, a2s, a2d, h2, b2, Wg, batch, out);
}

// Round 3
// 959.669 us; speedup vs baseline: 10.6440x; 1.0465x over previous
//
#include <hip/hip_runtime.h>
#include <hip/hip_bf16.h>
#include <math.h>

#define N_NODES 100000
#define N_EDGES 1600000
#define ET (N_EDGES + N_NODES)   // edges + self-loops
#define N_GRAPHS 512
#define NEG_SLOPE 0.2f
#define SCAN_BS 1024
#define NB_SCAN ((N_NODES + SCAN_BS - 1) / SCAN_BS)   // 98

__device__ __forceinline__ void atomAddF(float* p, float v) { unsafeAtomicAdd(p, v); }
__device__ __forceinline__ float lrelu(float v) { return v >= 0.f ? v : NEG_SLOPE * v; }

// bf16 helpers (RNE round)
__device__ __forceinline__ unsigned short f2bf(float f) {
    unsigned int u = __float_as_uint(f);
    u += 0x7FFFu + ((u >> 16) & 1u);
    return (unsigned short)(u >> 16);
}
__device__ __forceinline__ float bf2f(unsigned short s) {
    return __uint_as_float(((unsigned int)s) << 16);
}

// ---- init ----------------------------------------------------------------
__global__ void k_out_init(float* __restrict__ out, const float* __restrict__ bg) {
    int i = blockIdx.x * blockDim.x + threadIdx.x;
    if (i < N_GRAPHS) out[i] = bg[0];
}

// ---- CSR build -----------------------------------------------------------
__global__ __launch_bounds__(256) void k_deg(const int* __restrict__ ei, int* __restrict__ deg) {
    int e = blockIdx.x * 256 + threadIdx.x;
    if (e >= ET) return;
    int dst = (e < N_EDGES) ? ei[N_EDGES + e] : (e - N_EDGES);
    atomicAdd(deg + dst, 1);
}

__global__ __launch_bounds__(SCAN_BS) void k_scan1(const int* __restrict__ deg,
                                                   int* __restrict__ excl, int* __restrict__ bsum) {
    __shared__ int sh[SCAN_BS];
    const int t = threadIdx.x;
    const int i = blockIdx.x * SCAN_BS + t;
    int v = (i < N_NODES) ? deg[i] : 0;
    sh[t] = v;
    __syncthreads();
    for (int off = 1; off < SCAN_BS; off <<= 1) {
        int a = (t >= off) ? sh[t - off] : 0;
        __syncthreads();
        sh[t] += a;
        __syncthreads();
    }
    if (i < N_NODES) excl[i] = sh[t] - v;
    if (t == SCAN_BS - 1) bsum[blockIdx.x] = sh[t];
}

__global__ __launch_bounds__(128) void k_scan2(int* __restrict__ bsum) {
    __shared__ int sh[128];
    const int t = threadIdx.x;
    int v = (t < NB_SCAN) ? bsum[t] : 0;
    sh[t] = v;
    __syncthreads();
    for (int off = 1; off < 128; off <<= 1) {
        int a = (t >= off) ? sh[t - off] : 0;
        __syncthreads();
        sh[t] += a;
        __syncthreads();
    }
    if (t < NB_SCAN) bsum[t] = sh[t] - v;   // exclusive
}

__global__ __launch_bounds__(256) void k_scan3(const int* __restrict__ excl, const int* __restrict__ bsum,
                                               int* __restrict__ rowptr, int* __restrict__ cursor) {
    int i = blockIdx.x * 256 + threadIdx.x;
    if (i < N_NODES) {
        int r = excl[i] + bsum[i / SCAN_BS];
        rowptr[i] = r;
        cursor[i] = r;
    }
    if (i == 0) rowptr[N_NODES] = ET;
}

__global__ __launch_bounds__(256) void k_fill(const int* __restrict__ ei,
                                              int* __restrict__ cursor, int* __restrict__ ecol) {
    int e = blockIdx.x * 256 + threadIdx.x;
    if (e >= ET) return;
    int src, dst;
    if (e < N_EDGES) { src = ei[e]; dst = ei[N_EDGES + e]; }
    else             { src = dst = e - N_EDGES; }
    int slot = atomicAdd(cursor + dst, 1);
    ecol[slot] = src;
}

// ---- conv1 features: h1p = bf16(x@W1) [N,64]; a1s/a1d fp32 [N,8] ---------
__global__ __launch_bounds__(256) void k_feat1(
    const float* __restrict__ x, const float* __restrict__ W1,
    const float* __restrict__ as1, const float* __restrict__ ad1,
    unsigned short* __restrict__ h1p, float* __restrict__ a1s, float* __restrict__ a1d)
{
    __shared__ float xs[4][76];
    const int g = threadIdx.x >> 6;    // node sub-group (one wave each)
    const int c = threadIdx.x & 63;    // output channel
    const int n = blockIdx.x * 4 + g;  // grid = N/4 exactly
    const float* xr = x + (long)n * 75;
    xs[g][c] = xr[c];
    if (c < 11) xs[g][64 + c] = xr[64 + c];
    __syncthreads();
    float h = 0.f;
    #pragma unroll
    for (int k = 0; k < 75; ++k) h += xs[g][k] * W1[k * 64 + c];
    h1p[(long)n * 64 + c] = f2bf(h);
    const int head = c >> 3, lane = c & 7;
    float vs = h * as1[c];
    float vd = h * ad1[c];
    #pragma unroll
    for (int off = 1; off < 8; off <<= 1) {
        vs += __shfl_xor(vs, off, 64);
        vd += __shfl_xor(vd, off, 64);
    }
    if (lane == 0) { a1s[n * 8 + head] = vs; a1d[n * 8 + head] = vd; }
}

// ---- conv1 gather: one wave per dst; no max pass (softmax shift-invariant)
__global__ __launch_bounds__(256) void k_gat1(
    const int* __restrict__ rowptr, const int* __restrict__ ecol,
    const float* __restrict__ a1s, const float* __restrict__ a1d,
    const unsigned short* __restrict__ h1p, const float* __restrict__ bias1,
    float* __restrict__ x2)
{
    const int dst  = blockIdx.x * 4 + (threadIdx.x >> 6);  // grid = N/4
    const int lane = threadIdx.x & 63;
    const int beg = rowptr[dst], end = rowptr[dst + 1];
    const int head = lane >> 3;
    const float adc = a1d[(long)dst * 8 + head];
    float acc = 0.f, den = 0.f;
    for (int j = beg; j < end; ++j) {
        int s = ecol[j];
        float e  = lrelu(a1s[(long)s * 8 + head] + adc);
        float ee = __expf(e);
        den += ee;
        acc += ee * bf2f(h1p[(long)s * 64 + lane]);
    }
    float v = acc / den + bias1[lane];
    x2[(long)dst * 64 + lane] = v > 0.f ? v : (__expf(v) - 1.f);
}

// ---- conv2 features: one wave/node; lane c computes ch c and c+64 --------
// h2p[n*64+c] = pack(bf16(h[c]), bf16(h[c+64]))
__global__ __launch_bounds__(256) void k_feat2(
    const float* __restrict__ x2, const float* __restrict__ W2,
    const float* __restrict__ as2, const float* __restrict__ ad2,
    unsigned int* __restrict__ h2p, float* __restrict__ a2s, float* __restrict__ a2d)
{
    __shared__ float xs[4][64];
    const int g = threadIdx.x >> 6;
    const int c = threadIdx.x & 63;
    const int n = blockIdx.x * 4 + g;   // grid = N/4 exactly
    xs[g][c] = x2[(long)n * 64 + c];
    __syncthreads();
    float hlo = 0.f, hhi = 0.f;
    #pragma unroll
    for (int k = 0; k < 64; ++k) {
        float xv = xs[g][k];
        hlo += xv * W2[k * 128 + c];
        hhi += xv * W2[k * 128 + c + 64];
    }
    h2p[(long)n * 64 + c] = (unsigned int)f2bf(hlo) | ((unsigned int)f2bf(hhi) << 16);
    float vs = hlo * as2[c] + hhi * as2[c + 64];
    float vd = hlo * ad2[c] + hhi * ad2[c + 64];
    #pragma unroll
    for (int off = 1; off < 64; off <<= 1) {
        vs += __shfl_xor(vs, off, 64);
        vd += __shfl_xor(vd, off, 64);
    }
    if (c == 0) { a2s[n] = vs; a2d[n] = vd; }
}

// ---- conv2 gather + pool + linear, fully fused; no max pass --------------
__global__ __launch_bounds__(256) void k_gat2(
    const int* __restrict__ rowptr, const int* __restrict__ ecol,
    const float* __restrict__ a2s, const float* __restrict__ a2d,
    const unsigned int* __restrict__ h2p, const float* __restrict__ bias2,
    const float* __restrict__ Wg, const int* __restrict__ batch,
    float* __restrict__ out)
{
    const int dst  = blockIdx.x * 4 + (threadIdx.x >> 6);  // grid = N/4
    const int lane = threadIdx.x & 63;
    const int beg = rowptr[dst], end = rowptr[dst + 1];
    const float adv = a2d[dst];

    float acc0 = 0.f, acc1 = 0.f, den = 0.f;
    for (int j = beg; j < end; ++j) {
        int s = ecol[j];
        float ee = __expf(lrelu(a2s[s] + adv));
        den += ee;
        unsigned int pv = h2p[(long)s * 64 + lane];
        acc0 += ee * __uint_as_float(pv << 16);
        acc1 += ee * __uint_as_float(pv & 0xFFFF0000u);
    }
    const float inv = 1.f / den;
    float v0 = acc0 * inv + bias2[lane];
    float v1 = acc1 * inv + bias2[lane + 64];
    float s = v0 * Wg[lane] + v1 * Wg[lane + 64];
    #pragma unroll
    for (int off = 1; off < 64; off <<= 1) s += __shfl_xor(s, off, 64);
    if (lane == 0) atomAddF(out + batch[dst], s);
}

extern "C" void kernel_launch(void* const* d_in, const int* in_sizes, int n_in,
                              void* d_out, int out_size, void* d_ws, size_t ws_size,
                              hipStream_t stream) {
    (void)in_sizes; (void)n_in; (void)out_size; (void)ws_size;
    const float* x     = (const float*)d_in[0];
    const int*   ei    = (const int*)d_in[1];
    const int*   batch = (const int*)d_in[2];
    const float* W1    = (const float*)d_in[3];
    const float* as1   = (const float*)d_in[4];
    const float* ad1   = (const float*)d_in[5];
    const float* b1    = (const float*)d_in[6];
    const float* W2    = (const float*)d_in[7];
    const float* as2   = (const float*)d_in[8];
    const float* ad2   = (const float*)d_in[9];
    const float* b2    = (const float*)d_in[10];
    const float* Wg    = (const float*)d_in[11];
    const float* bg    = (const float*)d_in[12];
    float* out = (float*)d_out;

    // ---- workspace layout ----
    const long N = N_NODES;
    char* p = (char*)d_ws;
    int* deg    = (int*)p;              p += (N)      * sizeof(int);
    int* excl   = (int*)p;              p += (N)      * sizeof(int);
    int* rowptr = (int*)p;              p += (N + 1)  * sizeof(int);
    int* cursor = (int*)p;              p += (N)      * sizeof(int);
    int* bsum   = (int*)p;              p += 128      * sizeof(int);
    int* ecol   = (int*)p;              p += (long)ET * sizeof(int);
    unsigned short* h1p = (unsigned short*)p; p += N * 64 * sizeof(unsigned short);
    unsigned int*   h2p = (unsigned int*)p;   p += N * 64 * sizeof(unsigned int);
    float* a1s  = (float*)p;            p += N * 8    * sizeof(float);
    float* a1d  = (float*)p;            p += N * 8    * sizeof(float);
    float* x2   = (float*)p;            p += N * 64   * sizeof(float);
    float* a2s  = (float*)p;            p += N        * sizeof(float);
    float* a2d  = (float*)p;            p += N        * sizeof(float);

    // ---- CSR build (per call; ws re-poisoned before every launch) ----
    hipMemsetAsync(deg, 0, N * sizeof(int), stream);
    k_deg  <<<(ET + 255) / 256, 256, 0, stream>>>(ei, deg);
    k_scan1<<<NB_SCAN, SCAN_BS, 0, stream>>>(deg, excl, bsum);
    k_scan2<<<1, 128, 0, stream>>>(bsum);
    k_scan3<<<(N_NODES + 255) / 256, 256, 0, stream>>>(excl, bsum, rowptr, cursor);
    k_fill <<<(ET + 255) / 256, 256, 0, stream>>>(ei, cursor, ecol);

    // ---- conv1 ----
    k_feat1<<<N_NODES / 4, 256, 0, stream>>>(x, W1, as1, ad1, h1p, a1s, a1d);
    k_gat1 <<<N_NODES / 4, 256, 0, stream>>>(rowptr, ecol, a1s, a1d, h1p, b1, x2);

    // ---- conv2 + pool + linear ----
    k_feat2<<<N_NODES / 4, 256, 0, stream>>>(x2, W2, as2, ad2, h2p, a2s, a2d);
    k_out_init<<<2, 256, 0, stream>>>(out, bg);
    k_gat2 <<<N_NODES / 4, 256, 0, stream>>>(rowptr, ecol, a2s, a2d, h2p, b2, Wg, batch, out);
}

// Round 4
// 809.062 us; speedup vs baseline: 12.6254x; 1.1861x over previous
//
#include <hip/hip_runtime.h>
#include <hip/hip_bf16.h>
#include <math.h>

#define N_NODES 100000
#define N_EDGES 1600000
#define ET (N_EDGES + N_NODES)   // edges + self-loops
#define N_GRAPHS 512
#define NEG_SLOPE 0.2f
#define SCAN_BS 1024
#define NB_SCAN ((N_NODES + SCAN_BS - 1) / SCAN_BS)   // 98

__device__ __forceinline__ void atomAddF(float* p, float v) { unsafeAtomicAdd(p, v); }
__device__ __forceinline__ float lrelu(float v) { return v >= 0.f ? v : NEG_SLOPE * v; }

// bf16 helpers (RNE round)
__device__ __forceinline__ unsigned short f2bf(float f) {
    unsigned int u = __float_as_uint(f);
    u += 0x7FFFu + ((u >> 16) & 1u);
    return (unsigned short)(u >> 16);
}
__device__ __forceinline__ float bflo(unsigned int p) { return __uint_as_float(p << 16); }
__device__ __forceinline__ float bfhi(unsigned int p) { return __uint_as_float(p & 0xFFFF0000u); }

// ---- init ----------------------------------------------------------------
__global__ void k_out_init(float* __restrict__ out, const float* __restrict__ bg) {
    int i = blockIdx.x * blockDim.x + threadIdx.x;
    if (i < N_GRAPHS) out[i] = bg[0];
}

// ---- CSR build -----------------------------------------------------------
__global__ __launch_bounds__(256) void k_deg(const int* __restrict__ ei, int* __restrict__ deg) {
    int e = blockIdx.x * 256 + threadIdx.x;
    if (e >= ET) return;
    int dst = (e < N_EDGES) ? ei[N_EDGES + e] : (e - N_EDGES);
    atomicAdd(deg + dst, 1);
}

__global__ __launch_bounds__(SCAN_BS) void k_scan1(const int* __restrict__ deg,
                                                   int* __restrict__ excl, int* __restrict__ bsum) {
    __shared__ int sh[SCAN_BS];
    const int t = threadIdx.x;
    const int i = blockIdx.x * SCAN_BS + t;
    int v = (i < N_NODES) ? deg[i] : 0;
    sh[t] = v;
    __syncthreads();
    for (int off = 1; off < SCAN_BS; off <<= 1) {
        int a = (t >= off) ? sh[t - off] : 0;
        __syncthreads();
        sh[t] += a;
        __syncthreads();
    }
    if (i < N_NODES) excl[i] = sh[t] - v;
    if (t == SCAN_BS - 1) bsum[blockIdx.x] = sh[t];
}

__global__ __launch_bounds__(128) void k_scan2(int* __restrict__ bsum) {
    __shared__ int sh[128];
    const int t = threadIdx.x;
    int v = (t < NB_SCAN) ? bsum[t] : 0;
    sh[t] = v;
    __syncthreads();
    for (int off = 1; off < 128; off <<= 1) {
        int a = (t >= off) ? sh[t - off] : 0;
        __syncthreads();
        sh[t] += a;
        __syncthreads();
    }
    if (t < NB_SCAN) bsum[t] = sh[t] - v;   // exclusive
}

__global__ __launch_bounds__(256) void k_scan3(const int* __restrict__ excl, const int* __restrict__ bsum,
                                               int* __restrict__ rowptr, int* __restrict__ cursor) {
    int i = blockIdx.x * 256 + threadIdx.x;
    if (i < N_NODES) {
        int r = excl[i] + bsum[i / SCAN_BS];
        rowptr[i] = r;
        cursor[i] = r;
    }
    if (i == 0) rowptr[N_NODES] = ET;
}

__global__ __launch_bounds__(256) void k_fill(const int* __restrict__ ei,
                                              int* __restrict__ cursor, int* __restrict__ ecol) {
    int e = blockIdx.x * 256 + threadIdx.x;
    if (e >= ET) return;
    int src, dst;
    if (e < N_EDGES) { src = ei[e]; dst = ei[N_EDGES + e]; }
    else             { src = dst = e - N_EDGES; }
    int slot = atomicAdd(cursor + dst, 1);
    ecol[slot] = src;
}

// ---- conv1 features: h1p = bf16(x@W1) [N,64]; a1s/a1d fp32 [N,8] ---------
__global__ __launch_bounds__(256) void k_feat1(
    const float* __restrict__ x, const float* __restrict__ W1,
    const float* __restrict__ as1, const float* __restrict__ ad1,
    unsigned short* __restrict__ h1p, float* __restrict__ a1s, float* __restrict__ a1d)
{
    __shared__ float xs[4][76];
    const int g = threadIdx.x >> 6;
    const int c = threadIdx.x & 63;
    const int n = blockIdx.x * 4 + g;  // grid = N/4 exactly
    const float* xr = x + (long)n * 75;
    xs[g][c] = xr[c];
    if (c < 11) xs[g][64 + c] = xr[64 + c];
    __syncthreads();
    float h = 0.f;
    #pragma unroll
    for (int k = 0; k < 75; ++k) h += xs[g][k] * W1[k * 64 + c];
    h1p[(long)n * 64 + c] = f2bf(h);
    const int head = c >> 3, lane = c & 7;
    float vs = h * as1[c];
    float vd = h * ad1[c];
    #pragma unroll
    for (int off = 1; off < 8; off <<= 1) {
        vs += __shfl_xor(vs, off, 64);
        vd += __shfl_xor(vd, off, 64);
    }
    if (lane == 0) { a1s[n * 8 + head] = vs; a1d[n * 8 + head] = vd; }
}

// ---- conv1 gather: 8 edge-groups x 8 channel-lanes, software-pipelined ---
// lane = 8*g + l : group g handles edges beg+g, beg+g+8, ...; lane covers
// head l, channels 8l..8l+7 (one dwordx4 of packed bf16 per edge).
__global__ __launch_bounds__(256) void k_gat1(
    const int* __restrict__ rowptr, const int* __restrict__ ecol,
    const float* __restrict__ a1s, const float* __restrict__ a1d,
    const unsigned short* __restrict__ h1p, const float* __restrict__ bias1,
    float* __restrict__ x2)
{
    const int dst  = blockIdx.x * 4 + (threadIdx.x >> 6);  // grid = N/4
    const int lane = threadIdx.x & 63;
    const int g = lane >> 3;
    const int l = lane & 7;
    const int beg = rowptr[dst], end = rowptr[dst + 1];
    const float adc = a1d[(long)dst * 8 + l];

    float acc[8] = {0.f,0.f,0.f,0.f,0.f,0.f,0.f,0.f};
    float den = 0.f;

    int j = beg + g;
    bool v = (j < end);
    int s = v ? ecol[j] : 0;
    float av = a1s[(long)s * 8 + l];
    uint4 pv = *(const uint4*)(h1p + (long)s * 64 + l * 8);

    for (int j0 = beg; j0 < end; j0 += 8) {
        // stage next batch (loads issue while current math runs)
        int jn = j + 8;
        bool vn = (jn < end);
        int sn = vn ? ecol[jn] : 0;
        float avn = a1s[(long)sn * 8 + l];
        uint4 pvn = *(const uint4*)(h1p + (long)sn * 64 + l * 8);
        // compute current batch (8 edges in parallel across groups)
        float ee = v ? __expf(lrelu(av + adc)) : 0.f;
        den += ee;
        acc[0] += ee * bflo(pv.x); acc[1] += ee * bfhi(pv.x);
        acc[2] += ee * bflo(pv.y); acc[3] += ee * bfhi(pv.y);
        acc[4] += ee * bflo(pv.z); acc[5] += ee * bfhi(pv.z);
        acc[6] += ee * bflo(pv.w); acc[7] += ee * bfhi(pv.w);
        j = jn; v = vn; s = sn; av = avn; pv = pvn;
    }

    // reduce across edge-groups (lanes with same l): xor 8,16,32
    #pragma unroll
    for (int off = 8; off <= 32; off <<= 1) {
        den += __shfl_xor(den, off, 64);
        #pragma unroll
        for (int k = 0; k < 8; ++k) acc[k] += __shfl_xor(acc[k], off, 64);
    }

    if (g == 0) {
        const float inv = 1.f / den;
        float o[8];
        #pragma unroll
        for (int k = 0; k < 8; ++k) {
            float vv = acc[k] * inv + bias1[l * 8 + k];
            o[k] = vv > 0.f ? vv : (__expf(vv) - 1.f);
        }
        float4* xo = (float4*)(x2 + (long)dst * 64 + l * 8);
        xo[0] = make_float4(o[0], o[1], o[2], o[3]);
        xo[1] = make_float4(o[4], o[5], o[6], o[7]);
    }
}

// ---- conv2 features: one wave/node; lane c computes ch c and c+64 --------
__global__ __launch_bounds__(256) void k_feat2(
    const float* __restrict__ x2, const float* __restrict__ W2,
    const float* __restrict__ as2, const float* __restrict__ ad2,
    unsigned int* __restrict__ h2p, float* __restrict__ a2s, float* __restrict__ a2d)
{
    __shared__ float xs[4][64];
    const int g = threadIdx.x >> 6;
    const int c = threadIdx.x & 63;
    const int n = blockIdx.x * 4 + g;   // grid = N/4 exactly
    xs[g][c] = x2[(long)n * 64 + c];
    __syncthreads();
    float hlo = 0.f, hhi = 0.f;
    #pragma unroll
    for (int k = 0; k < 64; ++k) {
        float xv = xs[g][k];
        hlo += xv * W2[k * 128 + c];
        hhi += xv * W2[k * 128 + c + 64];
    }
    h2p[(long)n * 64 + c] = (unsigned int)f2bf(hlo) | ((unsigned int)f2bf(hhi) << 16);
    float vs = hlo * as2[c] + hhi * as2[c + 64];
    float vd = hlo * ad2[c] + hhi * ad2[c + 64];
    #pragma unroll
    for (int off = 1; off < 64; off <<= 1) {
        vs += __shfl_xor(vs, off, 64);
        vd += __shfl_xor(vd, off, 64);
    }
    if (c == 0) { a2s[n] = vs; a2d[n] = vd; }
}

// ---- conv2 gather + pool + linear: 4 edge-groups x 16 channel-lanes ------
// lane = 16*g + l : group g handles edges beg+g, beg+g+4, ...; lane covers
// packed channel pairs (4l..4l+3, +64) = one dwordx4 of h2p per edge.
__global__ __launch_bounds__(256) void k_gat2(
    const int* __restrict__ rowptr, const int* __restrict__ ecol,
    const float* __restrict__ a2s, const float* __restrict__ a2d,
    const unsigned int* __restrict__ h2p, const float* __restrict__ bias2,
    const float* __restrict__ Wg, const int* __restrict__ batch,
    float* __restrict__ out)
{
    const int dst  = blockIdx.x * 4 + (threadIdx.x >> 6);  // grid = N/4
    const int lane = threadIdx.x & 63;
    const int g = lane >> 4;
    const int l = lane & 15;
    const int beg = rowptr[dst], end = rowptr[dst + 1];
    const float adv = a2d[dst];

    float acc[8] = {0.f,0.f,0.f,0.f,0.f,0.f,0.f,0.f};
    float den = 0.f;

    int j = beg + g;
    bool v = (j < end);
    int s = v ? ecol[j] : 0;
    float av = a2s[s];
    uint4 pv = *(const uint4*)(h2p + (long)s * 64 + l * 4);

    for (int j0 = beg; j0 < end; j0 += 4) {
        int jn = j + 4;
        bool vn = (jn < end);
        int sn = vn ? ecol[jn] : 0;
        float avn = a2s[sn];
        uint4 pvn = *(const uint4*)(h2p + (long)sn * 64 + l * 4);
        float ee = v ? __expf(lrelu(av + adv)) : 0.f;
        den += ee;   // counted once per lane -> 16x overcount, fixed below
        acc[0] += ee * bflo(pv.x); acc[1] += ee * bfhi(pv.x);
        acc[2] += ee * bflo(pv.y); acc[3] += ee * bfhi(pv.y);
        acc[4] += ee * bflo(pv.z); acc[5] += ee * bfhi(pv.z);
        acc[6] += ee * bflo(pv.w); acc[7] += ee * bfhi(pv.w);
        j = jn; v = vn; s = sn; av = avn; pv = pvn;
    }

    // per-lane partial dot with Wg: acc[2t] = ch 4l+t, acc[2t+1] = ch 4l+t+64
    float dot = 0.f;
    #pragma unroll
    for (int t = 0; t < 4; ++t) {
        dot += acc[2 * t]     * Wg[4 * l + t];
        dot += acc[2 * t + 1] * Wg[4 * l + t + 64];
    }
    // bias2 . Wg constant (folded: out_node = inv*dot + sum(bias2*Wg))
    float bc = bias2[lane] * Wg[lane] + bias2[lane + 64] * Wg[lane + 64];
    #pragma unroll
    for (int off = 1; off < 64; off <<= 1) {
        den += __shfl_xor(den, off, 64);
        dot += __shfl_xor(dot, off, 64);
        bc  += __shfl_xor(bc,  off, 64);
    }
    if (lane == 0) atomAddF(out + batch[dst], dot * (16.f / den) + bc);
}

extern "C" void kernel_launch(void* const* d_in, const int* in_sizes, int n_in,
                              void* d_out, int out_size, void* d_ws, size_t ws_size,
                              hipStream_t stream) {
    (void)in_sizes; (void)n_in; (void)out_size; (void)ws_size;
    const float* x     = (const float*)d_in[0];
    const int*   ei    = (const int*)d_in[1];
    const int*   batch = (const int*)d_in[2];
    const float* W1    = (const float*)d_in[3];
    const float* as1   = (const float*)d_in[4];
    const float* ad1   = (const float*)d_in[5];
    const float* b1    = (const float*)d_in[6];
    const float* W2    = (const float*)d_in[7];
    const float* as2   = (const float*)d_in[8];
    const float* ad2   = (const float*)d_in[9];
    const float* b2    = (const float*)d_in[10];
    const float* Wg    = (const float*)d_in[11];
    const float* bg    = (const float*)d_in[12];
    float* out = (float*)d_out;

    // ---- workspace layout (16-B alignment maintained for h1p/h2p) ----
    const long N = N_NODES;
    char* p = (char*)d_ws;
    int* deg    = (int*)p;              p += (N)      * sizeof(int);
    int* excl   = (int*)p;              p += (N)      * sizeof(int);
    int* rowptr = (int*)p;              p += (N + 4)  * sizeof(int);   // +4: keep 16B align
    int* cursor = (int*)p;              p += (N)      * sizeof(int);
    int* bsum   = (int*)p;              p += 128      * sizeof(int);
    int* ecol   = (int*)p;              p += (long)ET * sizeof(int);
    unsigned short* h1p = (unsigned short*)p; p += N * 64 * sizeof(unsigned short);
    unsigned int*   h2p = (unsigned int*)p;   p += N * 64 * sizeof(unsigned int);
    float* a1s  = (float*)p;            p += N * 8    * sizeof(float);
    float* a1d  = (float*)p;            p += N * 8    * sizeof(float);
    float* x2   = (float*)p;            p += N * 64   * sizeof(float);
    float* a2s  = (float*)p;            p += N        * sizeof(float);
    float* a2d  = (float*)p;            p += N        * sizeof(float);

    // ---- CSR build ----
    hipMemsetAsync(deg, 0, N * sizeof(int), stream);
    k_deg  <<<(ET + 255) / 256, 256, 0, stream>>>(ei, deg);
    k_scan1<<<NB_SCAN, SCAN_BS, 0, stream>>>(deg, excl, bsum);
    k_scan2<<<1, 128, 0, stream>>>(bsum);
    k_scan3<<<(N_NODES + 255) / 256, 256, 0, stream>>>(excl, bsum, rowptr, cursor);
    k_fill <<<(ET + 255) / 256, 256, 0, stream>>>(ei, cursor, ecol);

    // ---- conv1 ----
    k_feat1<<<N_NODES / 4, 256, 0, stream>>>(x, W1, as1, ad1, h1p, a1s, a1d);
    k_gat1 <<<N_NODES / 4, 256, 0, stream>>>(rowptr, ecol, a1s, a1d, h1p, b1, x2);

    // ---- conv2 + pool + linear ----
    k_feat2<<<N_NODES / 4, 256, 0, stream>>>(x2, W2, as2, ad2, h2p, a2s, a2d);
    k_out_init<<<2, 256, 0, stream>>>(out, bg);
    k_gat2 <<<N_NODES / 4, 256, 0, stream>>>(rowptr, ecol, a2s, a2d, h2p, b2, Wg, batch, out);
}